// Round 1
// baseline (241.057 us; speedup 1.0000x reference)
//
#include <hip/hip_runtime.h>

// LightweightConv1d: y[b,t,c] = sum_k softmax(w)[c%H,k] * x[b, t+k-PAD, c]
// x: (B,T,C) fp32 contiguous (C innermost), w: (H,1,K) fp32, y: (B,T,C) fp32.
// Memory-bound: ~268 MB min traffic -> ~43 us roofline at 6.3 TB/s.

constexpr int B_   = 8;
constexpr int T_   = 4096;
constexpr int C_   = 1024;
constexpr int H_   = 16;
constexpr int K_   = 7;
constexpr int PAD_ = 3;
constexpr int TCHUNK = 32;          // outputs per thread along T
constexpr int C4 = C_ / 4;          // 256 float4 per row == blockDim.x

__global__ __launch_bounds__(256) void lwconv_kernel(
    const float* __restrict__ x, const float* __restrict__ w,
    float* __restrict__ y) {
  __shared__ float ws[H_][K_];
  const int tid = threadIdx.x;

  // Per-head softmax over K (112 values total; threads 0..15 each do one head).
  if (tid < H_) {
    float v[K_];
    float m = -1e30f;
#pragma unroll
    for (int k = 0; k < K_; ++k) { v[k] = w[tid * K_ + k]; m = fmaxf(m, v[k]); }
    float s = 0.f;
#pragma unroll
    for (int k = 0; k < K_; ++k) { v[k] = expf(v[k] - m); s += v[k]; }
    const float inv = 1.f / s;
#pragma unroll
    for (int k = 0; k < K_; ++k) ws[tid][k] = v[k] * inv;
  }
  __syncthreads();

  // Thread handles 4 consecutive channels c = 4*tid .. 4*tid+3.
  // Heads for those channels: (4*tid)%16 .. +3 (never wraps since 4 | 16).
  const int h0 = (4 * tid) & (H_ - 1);
  float wr[4][K_];
#pragma unroll
  for (int j = 0; j < 4; ++j)
#pragma unroll
    for (int k = 0; k < K_; ++k) wr[j][k] = ws[h0 + j][k];

  const int nchunks = T_ / TCHUNK;
  const int b  = blockIdx.x / nchunks;
  const int t0 = (blockIdx.x % nchunks) * TCHUNK;

  const float4* __restrict__ xr =
      reinterpret_cast<const float4*>(x + (size_t)b * T_ * C_) + tid;
  float4* __restrict__ yr =
      reinterpret_cast<float4*>(y + (size_t)b * T_ * C_) + tid;

  const float4 z4 = make_float4(0.f, 0.f, 0.f, 0.f);

  // Sliding window of K_ rows in registers (28 VGPRs).
  float4 win[K_];
#pragma unroll
  for (int i = 0; i < K_; ++i) {
    const int t = t0 - PAD_ + i;
    win[i] = (t >= 0 && t < T_) ? xr[(size_t)t * C4] : z4;
  }

  for (int tt = 0; tt < TCHUNK; ++tt) {
    // Prefetch next row (1-iteration distance) before the FMAs.
    const int tn = t0 + tt + 1 + PAD_;
    const float4 nxt = (tn < T_) ? xr[(size_t)tn * C4] : z4;

    float ax = 0.f, ay = 0.f, az = 0.f, aw = 0.f;
#pragma unroll
    for (int k = 0; k < K_; ++k) {
      ax = fmaf(win[k].x, wr[0][k], ax);
      ay = fmaf(win[k].y, wr[1][k], ay);
      az = fmaf(win[k].z, wr[2][k], az);
      aw = fmaf(win[k].w, wr[3][k], aw);
    }
    yr[(size_t)(t0 + tt) * C4] = make_float4(ax, ay, az, aw);

#pragma unroll
    for (int i = 0; i < K_ - 1; ++i) win[i] = win[i + 1];
    win[K_ - 1] = nxt;
  }
}

extern "C" void kernel_launch(void* const* d_in, const int* in_sizes, int n_in,
                              void* d_out, int out_size, void* d_ws, size_t ws_size,
                              hipStream_t stream) {
  const float* x = (const float*)d_in[0];   // (B,T,C) fp32
  const float* w = (const float*)d_in[1];   // (H,1,K) fp32
  float* y = (float*)d_out;                 // (B,T,C) fp32

  const int grid = B_ * (T_ / TCHUNK);      // 1024 blocks
  lwconv_kernel<<<grid, 256, 0, stream>>>(x, w, y);
}

// Round 2
// 233.169 us; speedup vs baseline: 1.0338x; 1.0338x over previous
//
#include <hip/hip_runtime.h>

// LightweightConv1d: y[b,t,c] = sum_k softmax(w)[c%H,k] * x[b, t+k-PAD, c]
// x: (B,T,C) fp32 contiguous (C innermost), w: (H,1,K) fp32, y: (B,T,C) fp32.
// Memory-bound: ~220 MB HBM traffic -> ~35-43 us roofline at 6.3 TB/s.
// R1 post-mortem: 85 us @ 2.6 TB/s, latency-bound (prefetch depth 1, 16 waves/CU).
// R2: batch-load 14 rows/thread (14 loads in flight) + TCHUNK=8 (4096 blocks).

constexpr int B_   = 8;
constexpr int T_   = 4096;
constexpr int C_   = 1024;
constexpr int H_   = 16;
constexpr int K_   = 7;
constexpr int PAD_ = 3;
constexpr int TCHUNK = 8;           // outputs per thread along T
constexpr int W_  = TCHUNK + K_ - 1;  // 14 input rows per chunk
constexpr int C4 = C_ / 4;          // 256 float4 per row == blockDim.x

__global__ __launch_bounds__(256, 4) void lwconv_kernel(
    const float* __restrict__ x, const float* __restrict__ w,
    float* __restrict__ y) {
  __shared__ float ws[H_][K_];
  const int tid = threadIdx.x;

  // Per-head softmax over K (112 values total; threads 0..15 each do one head).
  if (tid < H_) {
    float v[K_];
    float m = -1e30f;
#pragma unroll
    for (int k = 0; k < K_; ++k) { v[k] = w[tid * K_ + k]; m = fmaxf(m, v[k]); }
    float s = 0.f;
#pragma unroll
    for (int k = 0; k < K_; ++k) { v[k] = expf(v[k] - m); s += v[k]; }
    const float inv = 1.f / s;
#pragma unroll
    for (int k = 0; k < K_; ++k) ws[tid][k] = v[k] * inv;
  }
  __syncthreads();

  // Thread handles 4 consecutive channels c = 4*tid .. 4*tid+3.
  // Heads for those channels: (4*tid)%16 .. +3 (never wraps since 4 | 16).
  const int h0 = (4 * tid) & (H_ - 1);
  float wr[4][K_];
#pragma unroll
  for (int j = 0; j < 4; ++j)
#pragma unroll
    for (int k = 0; k < K_; ++k) wr[j][k] = ws[h0 + j][k];

  const int nchunks = T_ / TCHUNK;          // 512
  const int b  = blockIdx.x / nchunks;
  const int t0 = (blockIdx.x % nchunks) * TCHUNK;

  const float4* __restrict__ xr =
      reinterpret_cast<const float4*>(x + (size_t)b * T_ * C_) + tid;
  float4* __restrict__ yr =
      reinterpret_cast<float4*>(y + (size_t)b * T_ * C_) + tid;

  const float4 z4 = make_float4(0.f, 0.f, 0.f, 0.f);

  // Batch-load all W_=14 input rows -> 14 outstanding global loads per wave
  // (14 KB in flight/wave; MLP is what R1 lacked).
  float4 win[W_];
#pragma unroll
  for (int i = 0; i < W_; ++i) {
    const int t = t0 - PAD_ + i;
    win[i] = (t >= 0 && t < T_) ? xr[(size_t)t * C4] : z4;
  }

#pragma unroll
  for (int tt = 0; tt < TCHUNK; ++tt) {
    float ax = 0.f, ay = 0.f, az = 0.f, aw = 0.f;
#pragma unroll
    for (int k = 0; k < K_; ++k) {
      ax = fmaf(win[tt + k].x, wr[0][k], ax);
      ay = fmaf(win[tt + k].y, wr[1][k], ay);
      az = fmaf(win[tt + k].z, wr[2][k], az);
      aw = fmaf(win[tt + k].w, wr[3][k], aw);
    }
    yr[(size_t)(t0 + tt) * C4] = make_float4(ax, ay, az, aw);
  }
}

extern "C" void kernel_launch(void* const* d_in, const int* in_sizes, int n_in,
                              void* d_out, int out_size, void* d_ws, size_t ws_size,
                              hipStream_t stream) {
  const float* x = (const float*)d_in[0];   // (B,T,C) fp32
  const float* w = (const float*)d_in[1];   // (H,1,K) fp32
  float* y = (float*)d_out;                 // (B,T,C) fp32

  const int grid = B_ * (T_ / TCHUNK);      // 4096 blocks
  lwconv_kernel<<<grid, 256, 0, stream>>>(x, w, y);
}